// Round 13
// baseline (260.515 us; speedup 1.0000x reference)
//
#include <hip/hip_runtime.h>

// GCN link predictor: z1 = relu(GCNConv(x,W1,b1)); z2 = GCNConv(z1,W2,b2);
// out[e] = dot(z2[src[e]], z2[dst[e]])
// R18 WIN (333->313.5): fused gemm2 into agg1 via 4KB LDS z1 tile.
// R19 WIN (313.5->304.2): gemm1 as M=16-tile/block, grid 6250, occ 70%.
// R20 WIN (304.2->292.8): gemm1 LDS A-staging, coalesced loads + swizzle.
// R21 WIN (292.8->282.6): dispatch packing (prep, scan merge, scatter|gemm1).
// R22 WIN (282.6->259.6): atomic-free scatter (deg's atomicAdd return IS the
//   slot); WRITE 66->47MB. Profile: scatgemm ~46, agg_gemm ~45, agg/decode
//   just below. Gathers run ~3.4TB/s effective, ~47% L2 hit on 25.6MB set.
// R23: gather critical-path + tail-packing bundle:
//   (1) csr index prefetch (depth-1 pipeline) in all three gather loops —
//       next group's indices load while current rows are in flight.
//   (2) agg/decode at 64 thr = 4 nodes = 1 wave (grid 25000): halves the
//       degree-tail max, doubles schedulable blocks.
//   (3) prep deg phase 8 edges/thread.
//   Gate: if gathers move <2us each, they're at the random-line request
//   floor -> next: boundary elimination or roofline.

typedef __attribute__((ext_vector_type(8))) short short8;  // 8 bf16 = 4 VGPRs
typedef __attribute__((ext_vector_type(4))) float f32x4;

__device__ __forceinline__ unsigned bf16_rne(float x) {
  unsigned u = __builtin_bit_cast(unsigned, x);
  return (u + 0x7FFFu + ((u >> 16) & 1u)) >> 16;
}
__device__ __forceinline__ float bf2f(unsigned short u) {
  return __builtin_bit_cast(float, ((unsigned)u) << 16);
}

// ---------- wpack body: W[128][128] fp32 -> bf16 hi/lo, MFMA B-frag order --
__device__ __forceinline__ void wpack_body(const float* __restrict__ W,
                                           short* __restrict__ Wp, int t) {
  int lane = t & 63;
  int kf = (t >> 6) & 3;
  int ct = t >> 8;
  int col = ct * 16 + (lane & 15);
  int k0 = kf * 32 + (lane >> 4) * 8;
  short* dh = Wp + ((((0 * 8 + ct) * 4 + kf) * 64) + lane) * 8;
  short* dl = Wp + ((((1 * 8 + ct) * 4 + kf) * 64) + lane) * 8;
  for (int j = 0; j < 8; ++j) {
    float w = W[(k0 + j) * 128 + col];
    unsigned h = bf16_rne(w);
    float hf = __builtin_bit_cast(float, h << 16);
    unsigned lo = bf16_rne(w - hf);
    dh[j] = (short)h;
    dl[j] = (short)lo;
  }
}

// ---------- prep: wpack(W1) | wpack(W2) | deg+slot (8 edges/thread) -------
__global__ __launch_bounds__(256) void prep_kernel(const float* __restrict__ W1,
                                                   short* __restrict__ Wp1,
                                                   const float* __restrict__ W2,
                                                   short* __restrict__ Wp2,
                                                   const int* __restrict__ dst,
                                                   int* __restrict__ deg,
                                                   int* __restrict__ slot, int E) {
  const int b = blockIdx.x;
  if (b < 8) {
    wpack_body(W1, Wp1, b * 256 + threadIdx.x);
  } else if (b < 16) {
    wpack_body(W2, Wp2, (b - 8) * 256 + threadIdx.x);
  } else {
    int base = (b - 16) * 2048 + threadIdx.x;
#pragma unroll
    for (int i = 0; i < 8; ++i) {
      int e = base + i * 256;
      if (e < E) slot[e] = atomicAdd(&deg[dst[e]], 1);
    }
  }
}

// ---------- block scan (512 elems/block) ----------
__global__ __launch_bounds__(512) void scan1_kernel(const int* __restrict__ in,
                                                    int* __restrict__ tmp,
                                                    int* __restrict__ bsums, int n) {
  __shared__ int sm[2][512];
  int t = threadIdx.x;
  int gid = blockIdx.x * 512 + t;
  int v = (gid < n) ? in[gid] : 0;
  int pp = 0;
  sm[0][t] = v;
  __syncthreads();
  for (int off = 1; off < 512; off <<= 1) {
    int nv = sm[pp][t];
    if (t >= off) nv += sm[pp][t - off];
    sm[pp ^ 1][t] = nv;
    pp ^= 1;
    __syncthreads();
  }
  int inc = sm[pp][t];
  if (gid < n) tmp[gid] = inc;
  if (t == 511) bsums[blockIdx.x] = inc;
}

// ---------- scan2+scan3 merged (nb <= 256) ----------
__global__ __launch_bounds__(256) void scan23_kernel(const int* __restrict__ tmp,
                                                     const int* __restrict__ bsums,
                                                     const int* __restrict__ deg,
                                                     int* __restrict__ rowptr,
                                                     float* __restrict__ dinv,
                                                     int n, int nb) {
  __shared__ int sm[2][256];
  __shared__ int orig[256];
  int t = threadIdx.x;
  int v = (t < nb) ? bsums[t] : 0;
  orig[t] = v;
  int pp = 0;
  sm[0][t] = v;
  __syncthreads();
  for (int off = 1; off < 256; off <<= 1) {
    int nv = sm[pp][t];
    if (t >= off) nv += sm[pp][t - off];
    sm[pp ^ 1][t] = nv;
    pp ^= 1;
    __syncthreads();
  }
  int gid = blockIdx.x * 256 + t;
  if (gid < n) {
    int b = gid >> 9;
    rowptr[gid + 1] = tmp[gid] + (sm[pp][b] - orig[b]);  // exclusive offset
    dinv[gid] = rsqrtf((float)(deg[gid] + 1));           // +1 self loop
  }
  if (gid == 0) rowptr[0] = 0;
}

// ---------- scatter(no-atomic) | gemm1 fused dispatch ----------
__global__ __launch_bounds__(256, 4) void scatgemm_kernel(
    const int* __restrict__ src, const int* __restrict__ dst,
    const int* __restrict__ rowptr, const int* __restrict__ slot,
    int2* __restrict__ csr, int E, int SCB, const float* __restrict__ A,
    const short* __restrict__ Wp, const float* __restrict__ dinv,
    unsigned short* __restrict__ out, int M) {
  __shared__ short8 lds_a[256];  // 4 KB (gemm path only)

  if ((int)blockIdx.x < SCB) {
    // ---- scatter path (atomic-free) ----
    int base = blockIdx.x * 1024 + threadIdx.x;
#pragma unroll
    for (int i = 0; i < 4; ++i) {
      int e = base + i * 256;
      if (e < E) {
        int d = dst[e];
        csr[rowptr[d] + slot[e]] = make_int2(src[e], e);
      }
    }
    return;
  }

  // ---- gemm1 path (R20: coalesced stage -> swizzled LDS -> MFMA) ----
  const int bid = blockIdx.x - SCB;
  const int tid = threadIdx.x;
  const int wave = tid >> 6;
  const int lane = tid & 63;
  const int quad = lane >> 4;
  const int l15 = lane & 15;
  const int ct0 = wave * 2;
  const int ct1 = wave * 2 + 1;
  const int colbase = wave * 32 + l15;
  const int rb0 = bid * 16;
  const bool full = (rb0 + 16 <= M);
  const short8* Wp8 = (const short8*)Wp;

  {
    const int row = tid >> 4;
    const int seg = tid & 15;
    float4 a0 = {0.f, 0.f, 0.f, 0.f}, a1 = {0.f, 0.f, 0.f, 0.f};
    if (full || rb0 + row < M) {
      const float4* p = (const float4*)A + (size_t)(rb0 + row) * 32 + seg * 2;
      a0 = p[0];
      a1 = p[1];
    }
    const float av[8] = {a0.x, a0.y, a0.z, a0.w, a1.x, a1.y, a1.z, a1.w};
    short8 w;
#pragma unroll
    for (int j = 0; j < 8; ++j) w[j] = (short)bf16_rne(av[j]);
    lds_a[row * 16 + (seg ^ (row & 7))] = w;
  }

  short8 bh0[4], bh1[4], bl0[4], bl1[4];
#pragma unroll
  for (int f = 0; f < 4; ++f) {
    bh0[f] = Wp8[((0 * 8 + ct0) * 4 + f) * 64 + lane];
    bh1[f] = Wp8[((0 * 8 + ct1) * 4 + f) * 64 + lane];
    bl0[f] = Wp8[((1 * 8 + ct0) * 4 + f) * 64 + lane];
    bl1[f] = Wp8[((1 * 8 + ct1) * 4 + f) * 64 + lane];
  }

  __syncthreads();

  short8 af[4];
#pragma unroll
  for (int f = 0; f < 4; ++f) af[f] = lds_a[l15 * 16 + ((f * 4 + quad) ^ (l15 & 7))];

  f32x4 a0h = {0.f, 0.f, 0.f, 0.f};
  f32x4 a0l = {0.f, 0.f, 0.f, 0.f};
  f32x4 a1h = {0.f, 0.f, 0.f, 0.f};
  f32x4 a1l = {0.f, 0.f, 0.f, 0.f};
#pragma unroll
  for (int f = 0; f < 4; ++f) {
    a0h = __builtin_amdgcn_mfma_f32_16x16x32_bf16(af[f], bh0[f], a0h, 0, 0, 0);
    a1h = __builtin_amdgcn_mfma_f32_16x16x32_bf16(af[f], bh1[f], a1h, 0, 0, 0);
    a0l = __builtin_amdgcn_mfma_f32_16x16x32_bf16(af[f], bl0[f], a0l, 0, 0, 0);
    a1l = __builtin_amdgcn_mfma_f32_16x16x32_bf16(af[f], bl1[f], a1l, 0, 0, 0);
  }

  if (full) {
    const f32x4 dv = *(const f32x4*)(dinv + rb0 + quad * 4);
#pragma unroll
    for (int i = 0; i < 4; ++i) {
      const int r = rb0 + quad * 4 + i;
      out[(size_t)r * 128 + colbase] =
          (unsigned short)bf16_rne((a0h[i] + a0l[i]) * dv[i]);
      out[(size_t)r * 128 + colbase + 16] =
          (unsigned short)bf16_rne((a1h[i] + a1l[i]) * dv[i]);
    }
  } else {
#pragma unroll
    for (int i = 0; i < 4; ++i) {
      const int r = rb0 + quad * 4 + i;
      if (r < M) {
        const float d = dinv[r];
        out[(size_t)r * 128 + colbase] =
            (unsigned short)bf16_rne((a0h[i] + a0l[i]) * d);
        out[(size_t)r * 128 + colbase + 16] =
            (unsigned short)bf16_rne((a1h[i] + a1l[i]) * d);
      }
    }
  }
}

// ---------- FUSED agg1 + gemm2, with csr index prefetch ----------
__global__ __launch_bounds__(256) void agg_gemm_kernel(
    const unsigned short* __restrict__ xw, const float* __restrict__ dinv,
    const int* __restrict__ rowptr, const int2* __restrict__ csr,
    const float* __restrict__ bias, const short* __restrict__ Wp,
    unsigned short* __restrict__ out, int N) {
  __shared__ short8 z1t[16][16];  // [row][chunk ^ row], 4 KB

  const int tid = threadIdx.x;
  const int node0 = blockIdx.x * 16;
  const int n = tid >> 4;
  const int l = tid & 15;
  const int node = node0 + n;

  short8 o = {0, 0, 0, 0, 0, 0, 0, 0};
  if (node < N) {
    const short8* xw8 = (const short8*)xw;
    short8 sv = xw8[(size_t)node * 16 + l];
    float acc[8];
#pragma unroll
    for (int j = 0; j < 8; ++j) acc[j] = bf2f((unsigned short)sv[j]);
    int s = rowptr[node], e = rowptr[node + 1];
    int k = s;
    // depth-1 csr prefetch pipeline
    int2 c0 = {0, 0}, c1 = {0, 0}, c2 = {0, 0}, c3 = {0, 0};
    bool have = (k + 4 <= e);
    if (have) { c0 = csr[k]; c1 = csr[k + 1]; c2 = csr[k + 2]; c3 = csr[k + 3]; }
    while (have) {
      const int kn = k + 4;
      const bool hn = (kn + 4 <= e);
      int2 n0 = {0, 0}, n1 = {0, 0}, n2 = {0, 0}, n3 = {0, 0};
      if (hn) { n0 = csr[kn]; n1 = csr[kn + 1]; n2 = csr[kn + 2]; n3 = csr[kn + 3]; }
      short8 v0 = xw8[(size_t)c0.x * 16 + l];
      short8 v1 = xw8[(size_t)c1.x * 16 + l];
      short8 v2 = xw8[(size_t)c2.x * 16 + l];
      short8 v3 = xw8[(size_t)c3.x * 16 + l];
#pragma unroll
      for (int j = 0; j < 8; ++j) {
        acc[j] += (bf2f((unsigned short)v0[j]) + bf2f((unsigned short)v1[j])) +
                  (bf2f((unsigned short)v2[j]) + bf2f((unsigned short)v3[j]));
      }
      k = kn; have = hn; c0 = n0; c1 = n1; c2 = n2; c3 = n3;
    }
    for (; k < e; ++k) {
      short8 v = xw8[(size_t)csr[k].x * 16 + l];
#pragma unroll
      for (int j = 0; j < 8; ++j) acc[j] += bf2f((unsigned short)v[j]);
    }
    float di = dinv[node];
    const float4* b4 = (const float4*)bias;
    float4 bb0 = b4[l * 2], bb1 = b4[l * 2 + 1];
    float bv[8] = {bb0.x, bb0.y, bb0.z, bb0.w, bb1.x, bb1.y, bb1.z, bb1.w};
#pragma unroll
    for (int j = 0; j < 8; ++j) {
      float v = fmaf(di, acc[j], bv[j]);
      v = fmaxf(v, 0.f);  // relu (layer 1)
      o[j] = (short)bf16_rne(v);
    }
  }
  z1t[n][l ^ n] = o;  // swizzled store
  __syncthreads();

  const int wave = tid >> 6;
  const int lane = tid & 63;
  const int quad = lane >> 4;
  const int l15 = lane & 15;
  const int ct0 = wave * 2;
  const int ct1 = wave * 2 + 1;

  short8 af[4];
#pragma unroll
  for (int f = 0; f < 4; ++f) af[f] = z1t[l15][(f * 4 + quad) ^ l15];

  const short8* Wp8 = (const short8*)Wp;
  f32x4 a0h = {0.f, 0.f, 0.f, 0.f};
  f32x4 a0l = {0.f, 0.f, 0.f, 0.f};
  f32x4 a1h = {0.f, 0.f, 0.f, 0.f};
  f32x4 a1l = {0.f, 0.f, 0.f, 0.f};
#pragma unroll
  for (int f = 0; f < 4; ++f) {
    const short8 bh0 = Wp8[((0 * 8 + ct0) * 4 + f) * 64 + lane];
    const short8 bh1 = Wp8[((0 * 8 + ct1) * 4 + f) * 64 + lane];
    const short8 bl0 = Wp8[((1 * 8 + ct0) * 4 + f) * 64 + lane];
    const short8 bl1 = Wp8[((1 * 8 + ct1) * 4 + f) * 64 + lane];
    a0h = __builtin_amdgcn_mfma_f32_16x16x32_bf16(af[f], bh0, a0h, 0, 0, 0);
    a1h = __builtin_amdgcn_mfma_f32_16x16x32_bf16(af[f], bh1, a1h, 0, 0, 0);
    a0l = __builtin_amdgcn_mfma_f32_16x16x32_bf16(af[f], bl0, a0l, 0, 0, 0);
    a1l = __builtin_amdgcn_mfma_f32_16x16x32_bf16(af[f], bl1, a1l, 0, 0, 0);
  }

  if (node0 + 16 <= N) {
    const f32x4 dv = *(const f32x4*)(dinv + node0 + quad * 4);
#pragma unroll
    for (int i = 0; i < 4; ++i) {
      const int r = node0 + quad * 4 + i;
      out[(size_t)r * 128 + ct0 * 16 + l15] =
          (unsigned short)bf16_rne((a0h[i] + a0l[i]) * dv[i]);
      out[(size_t)r * 128 + ct1 * 16 + l15] =
          (unsigned short)bf16_rne((a1h[i] + a1l[i]) * dv[i]);
    }
  } else {
#pragma unroll
    for (int i = 0; i < 4; ++i) {
      const int r = node0 + quad * 4 + i;
      if (r < N) {
        const float d = dinv[r];
        out[(size_t)r * 128 + ct0 * 16 + l15] =
            (unsigned short)bf16_rne((a0h[i] + a0l[i]) * d);
        out[(size_t)r * 128 + ct1 * 16 + l15] =
            (unsigned short)bf16_rne((a1h[i] + a1l[i]) * d);
      }
    }
  }
}

// ---------- layer-2 aggregation: 64 thr = 4 nodes = 1 wave ----------
__global__ __launch_bounds__(64) void agg_kernel(const unsigned short* __restrict__ xw,
                                                 const float* __restrict__ dinv,
                                                 const int* __restrict__ rowptr,
                                                 const int2* __restrict__ csr,
                                                 const float* __restrict__ bias,
                                                 unsigned short* __restrict__ out,
                                                 int relu, int N) {
  int node = blockIdx.x * 4 + (threadIdx.x >> 4);
  int l = threadIdx.x & 15;
  if (node >= N) return;
  const short8* xw8 = (const short8*)xw;
  short8 sv = xw8[(size_t)node * 16 + l];
  float acc[8];
#pragma unroll
  for (int j = 0; j < 8; ++j) acc[j] = bf2f((unsigned short)sv[j]);
  int s = rowptr[node], e = rowptr[node + 1];
  int k = s;
  int2 c0 = {0, 0}, c1 = {0, 0}, c2 = {0, 0}, c3 = {0, 0};
  bool have = (k + 4 <= e);
  if (have) { c0 = csr[k]; c1 = csr[k + 1]; c2 = csr[k + 2]; c3 = csr[k + 3]; }
  while (have) {
    const int kn = k + 4;
    const bool hn = (kn + 4 <= e);
    int2 n0 = {0, 0}, n1 = {0, 0}, n2 = {0, 0}, n3 = {0, 0};
    if (hn) { n0 = csr[kn]; n1 = csr[kn + 1]; n2 = csr[kn + 2]; n3 = csr[kn + 3]; }
    short8 v0 = xw8[(size_t)c0.x * 16 + l];
    short8 v1 = xw8[(size_t)c1.x * 16 + l];
    short8 v2 = xw8[(size_t)c2.x * 16 + l];
    short8 v3 = xw8[(size_t)c3.x * 16 + l];
#pragma unroll
    for (int j = 0; j < 8; ++j) {
      acc[j] += (bf2f((unsigned short)v0[j]) + bf2f((unsigned short)v1[j])) +
                (bf2f((unsigned short)v2[j]) + bf2f((unsigned short)v3[j]));
    }
    k = kn; have = hn; c0 = n0; c1 = n1; c2 = n2; c3 = n3;
  }
  for (; k < e; ++k) {
    short8 v = xw8[(size_t)csr[k].x * 16 + l];
#pragma unroll
    for (int j = 0; j < 8; ++j) acc[j] += bf2f((unsigned short)v[j]);
  }
  float di = dinv[node];
  const float4* b4 = (const float4*)bias;
  float4 bb0 = b4[l * 2], bb1 = b4[l * 2 + 1];
  float bv[8] = {bb0.x, bb0.y, bb0.z, bb0.w, bb1.x, bb1.y, bb1.z, bb1.w};
  short8 o;
#pragma unroll
  for (int j = 0; j < 8; ++j) {
    float v = fmaf(di, acc[j], bv[j]);
    if (relu) v = fmaxf(v, 0.f);
    o[j] = (short)bf16_rne(v);
  }
  ((short8*)out)[(size_t)node * 16 + l] = o;
}

// ---------- decode over dst-CSR: 64 thr = 4 nodes = 1 wave ----------
__global__ __launch_bounds__(64) void decode_kernel(const unsigned short* __restrict__ z,
                                                    const int* __restrict__ rowptr,
                                                    const int2* __restrict__ csr,
                                                    float* __restrict__ out, int N) {
  int node = blockIdx.x * 4 + (threadIdx.x >> 4);
  int l = threadIdx.x & 15;
  if (node >= N) return;
  const short8* z8 = (const short8*)z;
  short8 zv = z8[(size_t)node * 16 + l];
  float zd[8];
#pragma unroll
  for (int j = 0; j < 8; ++j) zd[j] = bf2f((unsigned short)zv[j]);
  int s = rowptr[node], e = rowptr[node + 1];
  int k = s;
  int2 c0 = {0, 0}, c1 = {0, 0}, c2 = {0, 0}, c3 = {0, 0};
  bool have = (k + 4 <= e);
  if (have) { c0 = csr[k]; c1 = csr[k + 1]; c2 = csr[k + 2]; c3 = csr[k + 3]; }
  while (have) {
    const int kn = k + 4;
    const bool hn = (kn + 4 <= e);
    int2 n0 = {0, 0}, n1 = {0, 0}, n2 = {0, 0}, n3 = {0, 0};
    if (hn) { n0 = csr[kn]; n1 = csr[kn + 1]; n2 = csr[kn + 2]; n3 = csr[kn + 3]; }
    short8 v0 = z8[(size_t)c0.x * 16 + l];
    short8 v1 = z8[(size_t)c1.x * 16 + l];
    short8 v2 = z8[(size_t)c2.x * 16 + l];
    short8 v3 = z8[(size_t)c3.x * 16 + l];
    float p0 = 0.f, p1 = 0.f, p2 = 0.f, p3 = 0.f;
#pragma unroll
    for (int j = 0; j < 8; ++j) {
      p0 = fmaf(zd[j], bf2f((unsigned short)v0[j]), p0);
      p1 = fmaf(zd[j], bf2f((unsigned short)v1[j]), p1);
      p2 = fmaf(zd[j], bf2f((unsigned short)v2[j]), p2);
      p3 = fmaf(zd[j], bf2f((unsigned short)v3[j]), p3);
    }
#pragma unroll
    for (int off = 8; off > 0; off >>= 1) {
      p0 += __shfl_xor(p0, off);
      p1 += __shfl_xor(p1, off);
      p2 += __shfl_xor(p2, off);
      p3 += __shfl_xor(p3, off);
    }
    if (l == 0) {
      out[c0.y] = p0;
      out[c1.y] = p1;
      out[c2.y] = p2;
      out[c3.y] = p3;
    }
    k = kn; have = hn; c0 = n0; c1 = n1; c2 = n2; c3 = n3;
  }
  for (; k < e; ++k) {
    int2 c = csr[k];
    short8 v = z8[(size_t)c.x * 16 + l];
    float p = 0.f;
#pragma unroll
    for (int j = 0; j < 8; ++j) p = fmaf(zd[j], bf2f((unsigned short)v[j]), p);
#pragma unroll
    for (int off = 8; off > 0; off >>= 1) p += __shfl_xor(p, off);
    if (l == 0) out[c.y] = p;
  }
}

extern "C" void kernel_launch(void* const* d_in, const int* in_sizes, int n_in,
                              void* d_out, int out_size, void* d_ws, size_t ws_size,
                              hipStream_t stream) {
  const float* x  = (const float*)d_in[0];
  const int*   ei = (const int*)d_in[1];
  const float* W1 = (const float*)d_in[2];
  const float* b1 = (const float*)d_in[3];
  const float* W2 = (const float*)d_in[4];
  const float* b2 = (const float*)d_in[5];

  const int N = in_sizes[0] / 128;
  const int E = in_sizes[1] / 2;
  const int* src = ei;
  const int* dst = ei + E;

  char* ws = (char*)d_ws;
  size_t off = 0;
  auto alloc = [&](size_t bytes) -> void* {
    void* p = ws + off;
    off += (bytes + 255) & ~(size_t)255;
    return p;
  };
  unsigned short* bufA = (unsigned short*)alloc((size_t)N * 128 * 2);
  unsigned short* bufB = (unsigned short*)alloc((size_t)N * 128 * 2);
  float* dinv    = (float*)alloc((size_t)N * 4);
  int*   rowptr  = (int*)alloc((size_t)(N + 1) * 4);
  int2*  csr     = (int2*)alloc((size_t)E * 8);
  short* Wp1     = (short*)alloc((size_t)2 * 8 * 4 * 64 * 8 * 2);
  short* Wp2     = (short*)alloc((size_t)2 * 8 * 4 * 64 * 8 * 2);
  int*   tmp     = (int*)alloc((size_t)N * 4);
  int*   slot    = (int*)alloc((size_t)E * 4);
  int*   deg     = (int*)alloc((size_t)N * 4);   // zeroed region starts here
  int*   bsums   = (int*)alloc(1024);
  size_t zbytes = ((char*)bsums + 1024) - (char*)deg;
  hipMemsetAsync(deg, 0, zbytes, stream);

  const int E4B = (E + 1023) / 1024;
  const int E8B = (E + 2047) / 2048;
  const int NB = (N + 255) / 256;
  const int SB = (N + 511) / 512;
  const int G16 = (N + 15) / 16;
  const int AB16 = (N + 15) / 16;
  const int AB4 = (N + 3) / 4;

  // prep: wpack(W1) | wpack(W2) | deg+slot in one dispatch
  prep_kernel<<<16 + E8B, 256, 0, stream>>>(W1, Wp1, W2, Wp2, dst, deg, slot, E);
  scan1_kernel<<<SB, 512, 0, stream>>>(deg, tmp, bsums, N);
  // scan2 folded into scan3
  scan23_kernel<<<NB, 256, 0, stream>>>(tmp, bsums, deg, rowptr, dinv, N, SB);
  // scatter(no-atomic) | gemm1 in one dispatch
  scatgemm_kernel<<<E4B + G16, 256, 0, stream>>>(src, dst, rowptr, slot, csr, E,
                                                 E4B, x, Wp1, dinv, bufA, N);
  // FUSED: agg layer1 (+b1, relu) -> z1 in LDS -> MFMA z1@W2
  agg_gemm_kernel<<<AB16, 256, 0, stream>>>(bufA, dinv, rowptr, csr, b1, Wp2,
                                            bufB, N);
  // layer 2 aggregation: bufA = z2
  agg_kernel<<<AB4, 64, 0, stream>>>(bufB, dinv, rowptr, csr, b2, bufA, 0, N);
  // decode over dst-CSR
  decode_kernel<<<AB4, 64, 0, stream>>>(bufA, rowptr, csr, (float*)d_out, N);
}